// Round 9
// baseline (38784.641 us; speedup 1.0000x reference)
//
#include <hip/hip_runtime.h>
#include <hip/hip_bf16.h>
#include <stdint.h>

typedef __hip_bfloat16 bf16;
typedef __attribute__((ext_vector_type(8))) short bf16x8;
typedef __attribute__((ext_vector_type(4))) float f32x4;
typedef __attribute__((ext_vector_type(8))) unsigned short us8;

#define NB 8192
#define NE 256
#define NH 1024

__device__ __forceinline__ float bf2f(unsigned short u) {
  union { unsigned int i; float f; } x; x.i = ((unsigned int)u) << 16; return x.f;
}
__device__ __forceinline__ float sigm(float x) {
  return __builtin_amdgcn_rcpf(1.f + __expf(-x));
}
__device__ __forceinline__ float tanh_f(float x) {
  return 1.f - 2.f * __builtin_amdgcn_rcpf(1.f + __expf(2.f * x));
}

#define BAR() __builtin_amdgcn_s_barrier()
#define LGKM0() do { asm volatile("s_waitcnt lgkmcnt(0)" ::: "memory"); \
                     __builtin_amdgcn_sched_barrier(0); } while (0)
#define VMW(N) asm volatile("s_waitcnt vmcnt(" #N ")" ::: "memory")

#define GLDS(G, S)                                                            \
  __builtin_amdgcn_global_load_lds(                                           \
      (const __attribute__((address_space(1))) void*)(G),                     \
      (__attribute__((address_space(3))) void*)(S), 16, 0, 0)

// read all 8 A-frags / 4 B-frags of buffer N (compile-time N); r6-validated
// swizzle: chunk' = (l>>4) ^ ((l15>>1)&3), 2-way max (free per m136).
#define LDAF(N)                                                               \
  do { _Pragma("unroll") for (int m_ = 0; m_ < 8; ++m_)                       \
    af[m_] = *(const bf16x8*)(Aarena + base_a + ((N)*16384 + m_ * 1024));     \
  } while (0)
#define LDBV(N)                                                               \
  do { _Pragma("unroll") for (int g_ = 0; g_ < 4; ++g_)                       \
    bv[g_] = *(const bf16x8*)(Barena + base_b + ((N)*16384 + g_ * 4096));     \
  } while (0)

#define MFMA32C()                                                             \
  do {                                                                        \
    __builtin_amdgcn_s_setprio(1);                                            \
    _Pragma("unroll") for (int m_ = 0; m_ < 8; ++m_)                          \
      _Pragma("unroll") for (int g_ = 0; g_ < 4; ++g_)                        \
        acc[m_][g_] = __builtin_amdgcn_mfma_f32_16x16x32_bf16(                \
            af[m_], bv[g_], acc[m_][g_], 0, 0, 0);                            \
    __builtin_amdgcn_s_setprio(0);                                            \
  } while (0)

struct CellP {
  const bf16* X; const bf16* Hin;
  const bf16* Wih; const bf16* Whh;
  const float* bias; float* Cst; bf16* Hout;
  int ldx, Kx, Kh, czero;
};

// ---- fused GEMM + LSTM cell, 256x256, BK=32 dbuf, 64KB LDS, 2 blocks/CU ----
// gates = X@Wih^T + Hin@Whh^T + bias ; c' = sig(f)*c + sig(i)*tanh(g); h = sig(o)*tanh(c')
// Simple m97-style loop: [stage(next); ds_read(cur); lgkm0; 32 MFMA; vmw(0); bar].
// Cross-block overlap (2 blocks/CU) hides the intra-block LDS<->MFMA lockstep.
// Dual-problem dispatch: blocks [0,512) run PA, [512,1024) run PB (encode-phase
// L1(t) || L0(t+1) fusion); solo launches pass grid=512 with PB=PA.
__global__ __launch_bounds__(512, 4) void k_cell(CellP PA, CellP PB)
{
  __shared__ bf16 As[2][256][32];
  __shared__ bf16 Bs[2][256][32];

  CellP p = (blockIdx.x < 512) ? PA : PB;

  const int tid = threadIdx.x;
  const int l = tid & 63;
  const int l15 = l & 15;
  const int wv = tid >> 6;          // wave 0..7
  const int wr = wv >> 2;           // M-half (0..1)
  const int nc = wv & 3;            // N-wave (16 hcols)

  // m-major XCD ownership (L2-resident A panels per XCD)
  const int bid = blockIdx.x & 511;
  const int xcd = bid & 7, jj = bid >> 3;
  const int m0 = (xcd * 4 + (jj & 3)) * 256;
  const int hc0 = (jj >> 2) * 64;

  const int NT = (p.Kx + p.Kh) >> 5;   // K-tiles of 32; always even here

  // staging: thread -> LDS row tid>>2 (+128 second sweep), linear dest tid*16;
  // global chunk inverse-swizzled (r6-validated): sch = (tid&3)^((tid>>3)&3)
  const int ra0 = tid >> 2;
  const int sch = (tid & 3) ^ ((tid >> 3) & 3);
  const bf16* pAx = p.X + (size_t)(m0 + ra0) * p.ldx + sch * 8;
  const bf16* pAh = p.Hin + (size_t)(m0 + ra0) * NH + sch * 8;
  const size_t rAx2 = (size_t)128 * p.ldx, rAh2 = (size_t)128 * NH;
  const int grow0 = (ra0 >> 6) * NH + hc0 + (ra0 & 63);  // gates 0/1; +2NH -> 2/3
  const bf16* pBx = p.Wih + (size_t)grow0 * p.Kx + sch * 8;
  const bf16* pBh = p.Whh + (size_t)grow0 * NH + sch * 8;
  const size_t rBx2 = (size_t)2 * NH * p.Kx, rBh2 = (size_t)2 * NH * NH;

  char* Aarena = (char*)&As[0][0][0];
  char* Barena = (char*)&Bs[0][0][0];

  // read-side (r6-validated): rows of 64B, swizzled chunk
  const int chp = (l >> 4) ^ ((l15 >> 1) & 3);
  const int base_a = (wr * 128 + l15) * 64 + chp * 16;
  const int base_b = (nc * 16 + l15) * 64 + chp * 16;

  f32x4 acc[8][4];
  f32x4 zero4 = {0.f, 0.f, 0.f, 0.f};
#pragma unroll
  for (int i = 0; i < 8; ++i)
#pragma unroll
    for (int j2 = 0; j2 < 4; ++j2) acc[i][j2] = zero4;

  // stage one K-tile (A 16KB + B 16KB), 4 GLDS/thread
  auto stage = [&](int buf, int kt) {
    int kc = kt << 5;
    char* da = Aarena + buf * 16384 + tid * 16;
    char* db = Barena + buf * 16384 + tid * 16;
    if (kc < p.Kx) {
      const bf16* a0 = pAx + kc;
      GLDS(a0, da); GLDS(a0 + rAx2, da + 8192);
      const bf16* b0 = pBx + kc;
      GLDS(b0, db); GLDS(b0 + rBx2, db + 8192);
    } else {
      const bf16* a0 = pAh + (kc - p.Kx);
      GLDS(a0, da); GLDS(a0 + rAh2, da + 8192);
      const bf16* b0 = pBh + (kc - p.Kx);
      GLDS(b0, db); GLDS(b0 + rBh2, db + 8192);
    }
  };

  bf16x8 af[8], bv[4];

  stage(0, 0);
  VMW(0);
  BAR();

  for (int kt = 0; kt < NT; kt += 2) {
    // even iter: consume buf0, stage kt+1 into buf1
    stage(1, kt + 1);
    LDAF(0); LDBV(0);
    LGKM0();
    MFMA32C();
    VMW(0);   // stage(kt+1) landed (issued ~full iter earlier, L2-warm)
    BAR();    // publish buf1

    // odd iter: consume buf1, stage kt+2 into buf0
    if (kt + 2 < NT) stage(0, kt + 2);
    LDAF(1); LDBV(1);
    LGKM0();
    MFMA32C();
    VMW(0);
    BAR();
  }

  // epilogue: acc[m][gate][r]; C/D layout col=lane&15, row=(lane>>4)*4+r
  const int ecol = hc0 + nc * 16 + l15;
  const float bi = p.bias[ecol];
  const float bff = p.bias[NH + ecol];
  const float bg = p.bias[2 * NH + ecol];
  const float bo = p.bias[3 * NH + ecol];
  const int r0 = m0 + wr * 128 + ((l >> 4) << 2);
#pragma unroll
  for (int m = 0; m < 8; ++m) {
#pragma unroll
    for (int r = 0; r < 4; ++r) {
      int row = r0 + m * 16 + r;
      size_t idx = (size_t)row * NH + ecol;
      float gi = sigm(acc[m][0][r] + bi);
      float gf = sigm(acc[m][1][r] + bff);
      float gg = tanh_f(acc[m][2][r] + bg);
      float go = sigm(acc[m][3][r] + bo);
      float cold = p.czero ? 0.f : p.Cst[idx];
      float cn = gf * cold + gi * gg;
      p.Cst[idx] = cn;
      p.Hout[idx] = __float2bfloat16(go * tanh_f(cn));
    }
  }
}

// ---------------- MLP decode head + displacement add + re-embed ----------------
__global__ __launch_bounds__(256) void k_mlp(
    const bf16* __restrict__ h1, const bf16* __restrict__ W1b, const float* __restrict__ b1,
    const float* __restrict__ W2, const float* __restrict__ b2,
    const float* __restrict__ W3, const float* __restrict__ b3,
    const float* __restrict__ cin, float* __restrict__ cout,
    float* __restrict__ preds, const float* __restrict__ Wemb,
    const float* __restrict__ bemb, bf16* __restrict__ embout)
{
  const int l = threadIdx.x & 63;
  const int row = blockIdx.x * 4 + (threadIdx.x >> 6);

  const us8* hp = (const us8*)(h1 + (size_t)row * NH + l * 16);
  us8 hv0 = hp[0], hv1 = hp[1];
  float h[16];
#pragma unroll
  for (int j = 0; j < 8; ++j) { h[j] = bf2f(hv0[j]); h[8 + j] = bf2f(hv1[j]); }

  float y1[32];
#pragma unroll
  for (int j = 0; j < 32; ++j) {
    const us8* wp = (const us8*)(W1b + (size_t)j * NH + l * 16);
    us8 w0 = wp[0], w1 = wp[1];
    float d = 0.f;
#pragma unroll
    for (int k = 0; k < 8; ++k) {
      d = fmaf(h[k], bf2f(w0[k]), d);
      d = fmaf(h[8 + k], bf2f(w1[k]), d);
    }
#pragma unroll
    for (int off2 = 32; off2 > 0; off2 >>= 1) d += __shfl_xor(d, off2);
    y1[j] = fmaxf(d + b1[j], 0.f);
  }

  float y2[16];
#pragma unroll
  for (int m = 0; m < 16; ++m) {
    float s = b2[m];
#pragma unroll
    for (int j = 0; j < 32; ++j) s = fmaf(W2[m * 32 + j], y1[j], s);
    y2[m] = fmaxf(s, 0.f);
  }
  float o0 = b3[0], o1 = b3[1];
#pragma unroll
  for (int k = 0; k < 16; ++k) {
    o0 = fmaf(W3[k], y2[k], o0);
    o1 = fmaf(W3[16 + k], y2[k], o1);
  }
  float n0 = cin[row * 2] + o0;
  float n1 = cin[row * 2 + 1] + o1;
  if (l == 0) {
    preds[row * 2] = n0; preds[row * 2 + 1] = n1;
    cout[row * 2] = n0;  cout[row * 2 + 1] = n1;
  }
#pragma unroll
  for (int q = 0; q < 4; ++q) {
    int e = l + q * 64;
    float v = fmaf(n0, Wemb[e * 2], fmaf(n1, Wemb[e * 2 + 1], bemb[e]));
    embout[(size_t)row * NE + e] = __float2bfloat16(fmaxf(v, 0.f));
  }
}

// ---------------- embedding of observed trajectory (all 8 steps) ----------------
__global__ void k_embed(const float* __restrict__ x, const float* __restrict__ W,
                        const float* __restrict__ b, bf16* __restrict__ out) {
  const int l = threadIdx.x & 63;
  const int row = (blockIdx.x * 256 + threadIdx.x) >> 6;
  float x0 = x[row * 2], x1 = x[row * 2 + 1];
#pragma unroll
  for (int q = 0; q < 4; ++q) {
    int e = l + q * 64;
    float v = fmaf(x0, W[e * 2], fmaf(x1, W[e * 2 + 1], b[e]));
    out[(size_t)row * NE + e] = __float2bfloat16(fmaxf(v, 0.f));
  }
}

__global__ void k_f2b(const float* __restrict__ in, bf16* __restrict__ out, int n) {
  int i = (blockIdx.x * 256 + threadIdx.x) * 4;
  if (i >= n) return;
  float4 v = *(const float4*)(in + i);
  out[i] = __float2bfloat16(v.x);
  out[i + 1] = __float2bfloat16(v.y);
  out[i + 2] = __float2bfloat16(v.z);
  out[i + 3] = __float2bfloat16(v.w);
}

__global__ void k_badd(const float* __restrict__ a, const float* __restrict__ b,
                       float* __restrict__ o, int n) {
  int i = blockIdx.x * 256 + threadIdx.x;
  if (i < n) o[i] = a[i] + b[i];
}

extern "C" void kernel_launch(void* const* d_in, const int* in_sizes, int n_in,
                              void* d_out, int out_size, void* d_ws, size_t ws_size,
                              hipStream_t stream) {
  const float* obs   = (const float*)d_in[0];
  const float* Wemb  = (const float*)d_in[1];
  const float* bemb  = (const float*)d_in[2];
  const float* Wih0f = (const float*)d_in[3];
  const float* Whh0f = (const float*)d_in[4];
  const float* bih0  = (const float*)d_in[5];
  const float* bhh0  = (const float*)d_in[6];
  const float* Wih1f = (const float*)d_in[7];
  const float* Whh1f = (const float*)d_in[8];
  const float* bih1  = (const float*)d_in[9];
  const float* bhh1  = (const float*)d_in[10];
  const float* W1f   = (const float*)d_in[11];
  const float* b1m   = (const float*)d_in[12];
  const float* W2    = (const float*)d_in[13];
  const float* b2    = (const float*)d_in[14];
  const float* W3    = (const float*)d_in[15];
  const float* b3    = (const float*)d_in[16];

  char* ws = (char*)d_ws;
  size_t off = 0;
  auto alloc = [&](size_t bytes) -> void* {
    void* p = ws + off;
    off += (bytes + 255) & ~(size_t)255;
    return p;
  };
  bf16* wih0 = (bf16*)alloc((size_t)4096 * 256 * 2);
  bf16* whh0 = (bf16*)alloc((size_t)4096 * 1024 * 2);
  bf16* wih1 = (bf16*)alloc((size_t)4096 * 1024 * 2);
  bf16* whh1 = (bf16*)alloc((size_t)4096 * 1024 * 2);
  bf16* w1b  = (bf16*)alloc((size_t)32 * 1024 * 2);
  float* b0c = (float*)alloc((size_t)4096 * 4);
  float* b1c = (float*)alloc((size_t)4096 * 4);
  bf16* emb  = (bf16*)alloc((size_t)8 * NB * NE * 2);
  bf16* h0a  = (bf16*)alloc((size_t)NB * NH * 2);
  bf16* h0b  = (bf16*)alloc((size_t)NB * NH * 2);
  bf16* h1a  = (bf16*)alloc((size_t)NB * NH * 2);
  bf16* h1b  = (bf16*)alloc((size_t)NB * NH * 2);
  float* c0  = (float*)alloc((size_t)NB * NH * 4);
  float* c1  = (float*)alloc((size_t)NB * NH * 4);
  float* curr = (float*)alloc((size_t)NB * 2 * 4);
  bf16* cemb = (bf16*)alloc((size_t)NB * NE * 2);

  k_f2b<<<1024, 256, 0, stream>>>(Wih0f, wih0, 4096 * 256);
  k_f2b<<<4096, 256, 0, stream>>>(Whh0f, whh0, 4096 * 1024);
  k_f2b<<<4096, 256, 0, stream>>>(Wih1f, wih1, 4096 * 1024);
  k_f2b<<<4096, 256, 0, stream>>>(Whh1f, whh1, 4096 * 1024);
  k_f2b<<<32, 256, 0, stream>>>(W1f, w1b, 32 * 1024);
  k_badd<<<16, 256, 0, stream>>>(bih0, bhh0, b0c, 4096);
  k_badd<<<16, 256, 0, stream>>>(bih1, bhh1, b1c, 4096);
  k_embed<<<(8 * NB) / 4, 256, 0, stream>>>(obs, Wemb, bemb, emb);

  bf16* h0buf[2] = {h0a, h0b};
  bf16* h1buf[2] = {h1a, h1b};
  float* preds = (float*)d_out;

  auto mk = [&](const bf16* X, int ldx, int Kx, const bf16* Hin, int Kh,
                const bf16* Wih, const bf16* Whh, const float* bb, float* C,
                bf16* Ho, int cz) {
    CellP q;
    q.X = X; q.Hin = Hin; q.Wih = Wih; q.Whh = Whh;
    q.bias = bb; q.Cst = C; q.Hout = Ho;
    q.ldx = ldx; q.Kx = Kx; q.Kh = Kh; q.czero = cz;
    return q;
  };

  // L0(0): encode step 0, h/c start at zero
  {
    CellP p0 = mk(emb, NE, NE, h0buf[1], 0, wih0, whh0, b0c, c0, h0buf[0], 1);
    k_cell<<<512, 512, 0, stream>>>(p0, p0);
  }
  // encode: fused L1(t) || L0(t+1), t = 0..7 (both need only h0(t))
  for (int t = 0; t < 8; ++t) {
    int cu = t & 1, pv = cu ^ 1;
    int kh1 = (t == 0) ? 0 : NH;
    CellP pl1 = mk(h0buf[cu], NH, NH, h1buf[pv], kh1,
                   wih1, whh1, b1c, c1, h1buf[cu], t == 0);
    const bf16* xnext = (t + 1 < 8) ? emb + (size_t)(t + 1) * NB * NE
                                    : emb + (size_t)7 * NB * NE;  // t+1==8: embed(obs[-1])
    CellP pl0 = mk(xnext, NE, NE, h0buf[cu], NH,
                   wih0, whh0, b0c, c0, h0buf[pv], 0);
    k_cell<<<1024, 512, 0, stream>>>(pl1, pl0);
  }
  // decode: serial (L0 input comes from k_mlp of previous step)
  for (int t = 8; t < 20; ++t) {
    int cu = t & 1, pv = cu ^ 1;
    if (t > 8) {
      CellP pl0 = mk(cemb, NE, NE, h0buf[pv], NH,
                     wih0, whh0, b0c, c0, h0buf[cu], 0);
      k_cell<<<512, 512, 0, stream>>>(pl0, pl0);
    }
    CellP pl1 = mk(h0buf[cu], NH, NH, h1buf[pv], NH,
                   wih1, whh1, b1c, c1, h1buf[cu], 0);
    k_cell<<<512, 512, 0, stream>>>(pl1, pl1);
    int pI = t - 8;
    const float* cin = (pI == 0) ? (obs + (size_t)7 * NB * 2) : curr;
    k_mlp<<<NB / 4, 256, 0, stream>>>(h1buf[cu], w1b, b1m, W2, b2, W3, b3,
                                      cin, curr, preds + (size_t)pI * NB * 2,
                                      Wemb, bemb, cemb);
  }
}

// Round 10
// 4994.126 us; speedup vs baseline: 7.7661x; 7.7661x over previous
//
#include <hip/hip_runtime.h>
#include <hip/hip_bf16.h>
#include <stdint.h>

typedef __hip_bfloat16 bf16;
typedef __attribute__((ext_vector_type(8))) short bf16x8;
typedef __attribute__((ext_vector_type(4))) float f32x4;
typedef __attribute__((ext_vector_type(8))) unsigned short us8;

#define NB 8192
#define NE 256
#define NH 1024

__device__ __forceinline__ float bf2f(unsigned short u) {
  union { unsigned int i; float f; } x; x.i = ((unsigned int)u) << 16; return x.f;
}
__device__ __forceinline__ float sigm(float x) {
  return __builtin_amdgcn_rcpf(1.f + __expf(-x));
}
__device__ __forceinline__ float tanh_f(float x) {
  return 1.f - 2.f * __builtin_amdgcn_rcpf(1.f + __expf(2.f * x));
}

#define BAR() __builtin_amdgcn_s_barrier()
#define FENCE() asm volatile("" ::: "memory")
// drain this wave's LDS reads before crossing the end-of-phase barrier (WAR
// safety); NO sched_barrier(0) — compiler keeps its progressive lgkmcnt
// scheduling for the MFMA operand waits (m97/m141 evidence).
#define LGKME() asm volatile("s_waitcnt lgkmcnt(0)" ::: "memory")
#define VMW(N) asm volatile("s_waitcnt vmcnt(" #N ")" ::: "memory")

#define GLDS(G, S)                                                            \
  __builtin_amdgcn_global_load_lds(                                           \
      (const __attribute__((address_space(1))) void*)(G),                     \
      (__attribute__((address_space(3))) void*)(S), 16, 0, 0)

// 32-MFMA cluster: one m-half (4 m-frags) x 4 gates x 2 k-slices (T5 setprio)
#define MFMA32(MH)                                                            \
  do {                                                                        \
    __builtin_amdgcn_s_setprio(1);                                            \
    _Pragma("unroll") for (int i_ = 0; i_ < 4; ++i_)                          \
      _Pragma("unroll") for (int g_ = 0; g_ < 4; ++g_) {                      \
        acc[(MH)*4 + i_][g_] = __builtin_amdgcn_mfma_f32_16x16x32_bf16(       \
            af[i_], bv[g_], acc[(MH)*4 + i_][g_], 0, 0, 0);                   \
        acc[(MH)*4 + i_][g_] = __builtin_amdgcn_mfma_f32_16x16x32_bf16(       \
            af[4 + i_], bv[4 + g_], acc[(MH)*4 + i_][g_], 0, 0, 0);           \
      }                                                                       \
    __builtin_amdgcn_s_setprio(0);                                            \
  } while (0)

// ds_read A-frags: 4 m-frags of m-half MH, both k-slices (XOR-swizzled)
#define LDA8(BUF, MH)                                                         \
  do {                                                                        \
    const char* Ab_ = (const char*)&As[BUF][0][0];                            \
    _Pragma("unroll") for (int i_ = 0; i_ < 4; ++i_) {                        \
      int ro_ = (wr * 128 + (MH)*64 + i_ * 16 + l15) * 128;                   \
      af[i_]     = *(const bf16x8*)(Ab_ + ro_ + co0);                         \
      af[4 + i_] = *(const bf16x8*)(Ab_ + ro_ + co1);                         \
    }                                                                         \
  } while (0)

// ds_read B-frags: 4 gates, both k-slices
#define LDB8(BUF)                                                             \
  do {                                                                        \
    const char* Bb_ = (const char*)&Bs[BUF][0][0];                            \
    _Pragma("unroll") for (int g_ = 0; g_ < 4; ++g_) {                        \
      int ro_ = (g_ * 64 + nc * 16 + l15) * 128;                              \
      bv[g_]     = *(const bf16x8*)(Bb_ + ro_ + co0);                         \
      bv[4 + g_] = *(const bf16x8*)(Bb_ + ro_ + co1);                         \
    }                                                                         \
  } while (0)

struct CellP {
  const bf16* X; const bf16* Hin;
  const bf16* Wih; const bf16* Whh;
  const float* bias; float* Cst; bf16* Hout;
  int ldx, Kx, Kh, czero;
};

// -------- fused GEMM + LSTM cell, 256x256, 4-phase/iter (r3 structure) ------
// gates = X@Wih^T + Hin@Whh^T + bias ; c' = sig(f)*c + sig(i)*tanh(g); h = sig(o)*tanh(c')
// Block: 256 M-rows x (64 hcols x 4 gates). 8 waves (2M x 4N), wave = 128x64.
// Phase: {ds_read; stage; BAR; MFMA (compiler-progressive lgkm waits);
//         lgkmcnt(0); (VMW); BAR}.
// Dual-problem dispatch: blocks [0,nA) run PA, rest run PB (encode fusion).
__global__ __launch_bounds__(512, 2) void k_cell(CellP PA, CellP PB, int nA)
{
  __shared__ bf16 As[2][256][64];
  __shared__ bf16 Bs[2][256][64];

  const CellP p = (blockIdx.x < (unsigned)nA) ? PA : PB;
  const int bid = (blockIdx.x < (unsigned)nA) ? blockIdx.x : (blockIdx.x - nA);

  const int tid = threadIdx.x;
  const int l = tid & 63;
  const int l15 = l & 15;
  const int wv = tid >> 6;
  const int wr = wv >> 2;
  const int nc = wv & 3;

  // m-major XCD ownership: XCD x owns m-tiles {4x..4x+3} x all hc (L2-fit A).
  const int xcd = bid & 7, j = bid >> 3;
  const int m0 = (xcd * 4 + (j & 3)) * 256;
  const int hc0 = (j >> 2) * 64;

  const int NT = (p.Kx + p.Kh) >> 6;
  const int T = NT >> 1;

  const int rowid = tid >> 3;
  const int ch = (tid & 7) ^ (rowid & 7);
  const int wv8 = wv * 8;

  const int co0 = (((l >> 4) + 0) ^ (l & 7)) * 16;
  const int co1 = (((l >> 4) + 4) ^ (l & 7)) * 16;

  f32x4 acc[8][4];
  f32x4 zero4 = {0.f, 0.f, 0.f, 0.f};
#pragma unroll
  for (int i = 0; i < 8; ++i)
#pragma unroll
    for (int j2 = 0; j2 < 4; ++j2) acc[i][j2] = zero4;

  auto stage_a = [&](int buf, int half, int kt) {
    int kc = kt << 6;
    const bf16* src; size_t ld;
    if (kc < p.Kx) { src = p.X + kc; ld = (size_t)p.ldx; }
    else           { src = p.Hin + (kc - p.Kx); ld = NH; }
#pragma unroll
    for (int rnd = 0; rnd < 2; ++rnd) {
      int tr = rnd * 128 + half * 64;
      const bf16* gp = src + (size_t)(m0 + tr + rowid) * ld + ch * 8;
      GLDS(gp, &As[buf][tr + wv8][0]);
    }
  };
  auto stage_b = [&](int buf, int half, int kt) {
    int kc = kt << 6;
    const bf16* src; size_t ld;
    if (kc < p.Kx) { src = p.Wih + kc; ld = (size_t)p.Kx; }
    else           { src = p.Whh + (kc - p.Kx); ld = NH; }
#pragma unroll
    for (int rnd = 0; rnd < 2; ++rnd) {
      int gate = rnd * 2 + half;
      const bf16* gp = src + (size_t)(gate * NH + hc0 + rowid) * ld + ch * 8;
      GLDS(gp, &Bs[buf][gate * 64 + wv8][0]);
    }
  };

  // prologue: full b0(kt0) + A1.h0(kt1)
  stage_a(0, 0, 0);
  stage_a(0, 1, 0);
  stage_b(0, 0, 0);
  stage_b(0, 1, 0);
  stage_a(1, 0, 1);
  VMW(2);
  BAR();

  for (int t = 0; t < T; ++t) {
    const int kt1 = 2 * t + 1;
    const bool last = (t == T - 1);
    bf16x8 af[8], bv[8];

    // Ph1: compute b0.mh0 ; stage A1.h1 + B1 (kt1)
    LDB8(0); LDA8(0, 0);
    stage_a(1, 1, kt1);
    stage_b(1, 0, kt1);
    stage_b(1, 1, kt1);
    FENCE(); BAR();
    MFMA32(0);
    LGKME();
    BAR();

    // Ph2: compute b0.mh1 ; stage A0.h0 (kt0+2)
    LDA8(0, 1);
    if (!last) stage_a(0, 0, kt1 + 1);
    FENCE(); BAR();
    MFMA32(1);
    LGKME();
    if (last) { VMW(0); } else { VMW(2); }  // complete b1(kt1); leave A0.h0
    BAR();

    // Ph3: compute b1.mh0 ; stage A0.h1 + B0 (kt0+2)
    LDB8(1); LDA8(1, 0);
    if (!last) {
      stage_a(0, 1, kt1 + 1);
      stage_b(0, 0, kt1 + 1);
      stage_b(0, 1, kt1 + 1);
    }
    FENCE(); BAR();
    MFMA32(0);
    LGKME();
    BAR();

    // Ph4: compute b1.mh1 ; stage A1.h0 (kt1+2)
    LDA8(1, 1);
    if (!last) stage_a(1, 0, kt1 + 2);
    FENCE(); BAR();
    MFMA32(1);
    LGKME();
    if (!last) { VMW(2); }  // complete b0(kt0+2); leave A1.h0(kt1+2)
    BAR();
  }

  // epilogue: acc[m][gate][r]; C/D layout col=lane&15, row=(lane>>4)*4+r
  const int ecol = hc0 + nc * 16 + l15;
  const float bi = p.bias[ecol];
  const float bff = p.bias[NH + ecol];
  const float bg = p.bias[2 * NH + ecol];
  const float bo = p.bias[3 * NH + ecol];
  const int r0 = m0 + wr * 128 + ((l >> 4) << 2);
#pragma unroll
  for (int m = 0; m < 8; ++m) {
#pragma unroll
    for (int r = 0; r < 4; ++r) {
      int row = r0 + m * 16 + r;
      size_t idx = (size_t)row * NH + ecol;
      float gi = sigm(acc[m][0][r] + bi);
      float gf = sigm(acc[m][1][r] + bff);
      float gg = tanh_f(acc[m][2][r] + bg);
      float go = sigm(acc[m][3][r] + bo);
      float cold = p.czero ? 0.f : p.Cst[idx];
      float cn = gf * cold + gi * gg;
      p.Cst[idx] = cn;
      p.Hout[idx] = __float2bfloat16(go * tanh_f(cn));
    }
  }
}

// ---------------- MLP decode head + displacement add + re-embed ----------------
__global__ __launch_bounds__(256) void k_mlp(
    const bf16* __restrict__ h1, const bf16* __restrict__ W1b, const float* __restrict__ b1,
    const float* __restrict__ W2, const float* __restrict__ b2,
    const float* __restrict__ W3, const float* __restrict__ b3,
    const float* __restrict__ cin, float* __restrict__ cout,
    float* __restrict__ preds, const float* __restrict__ Wemb,
    const float* __restrict__ bemb, bf16* __restrict__ embout)
{
  const int l = threadIdx.x & 63;
  const int row = blockIdx.x * 4 + (threadIdx.x >> 6);

  const us8* hp = (const us8*)(h1 + (size_t)row * NH + l * 16);
  us8 hv0 = hp[0], hv1 = hp[1];
  float h[16];
#pragma unroll
  for (int j = 0; j < 8; ++j) { h[j] = bf2f(hv0[j]); h[8 + j] = bf2f(hv1[j]); }

  float y1[32];
#pragma unroll
  for (int j = 0; j < 32; ++j) {
    const us8* wp = (const us8*)(W1b + (size_t)j * NH + l * 16);
    us8 w0 = wp[0], w1 = wp[1];
    float d = 0.f;
#pragma unroll
    for (int k = 0; k < 8; ++k) {
      d = fmaf(h[k], bf2f(w0[k]), d);
      d = fmaf(h[8 + k], bf2f(w1[k]), d);
    }
#pragma unroll
    for (int off2 = 32; off2 > 0; off2 >>= 1) d += __shfl_xor(d, off2);
    y1[j] = fmaxf(d + b1[j], 0.f);
  }

  float y2[16];
#pragma unroll
  for (int m = 0; m < 16; ++m) {
    float s = b2[m];
#pragma unroll
    for (int j = 0; j < 32; ++j) s = fmaf(W2[m * 32 + j], y1[j], s);
    y2[m] = fmaxf(s, 0.f);
  }
  float o0 = b3[0], o1 = b3[1];
#pragma unroll
  for (int k = 0; k < 16; ++k) {
    o0 = fmaf(W3[k], y2[k], o0);
    o1 = fmaf(W3[16 + k], y2[k], o1);
  }
  float n0 = cin[row * 2] + o0;
  float n1 = cin[row * 2 + 1] + o1;
  if (l == 0) {
    preds[row * 2] = n0; preds[row * 2 + 1] = n1;
    cout[row * 2] = n0;  cout[row * 2 + 1] = n1;
  }
#pragma unroll
  for (int q = 0; q < 4; ++q) {
    int e = l + q * 64;
    float v = fmaf(n0, Wemb[e * 2], fmaf(n1, Wemb[e * 2 + 1], bemb[e]));
    embout[(size_t)row * NE + e] = __float2bfloat16(fmaxf(v, 0.f));
  }
}

// ---------------- embedding of observed trajectory (all 8 steps) ----------------
__global__ void k_embed(const float* __restrict__ x, const float* __restrict__ W,
                        const float* __restrict__ b, bf16* __restrict__ out) {
  const int l = threadIdx.x & 63;
  const int row = (blockIdx.x * 256 + threadIdx.x) >> 6;
  float x0 = x[row * 2], x1 = x[row * 2 + 1];
#pragma unroll
  for (int q = 0; q < 4; ++q) {
    int e = l + q * 64;
    float v = fmaf(x0, W[e * 2], fmaf(x1, W[e * 2 + 1], b[e]));
    out[(size_t)row * NE + e] = __float2bfloat16(fmaxf(v, 0.f));
  }
}

__global__ void k_f2b(const float* __restrict__ in, bf16* __restrict__ out, int n) {
  int i = (blockIdx.x * 256 + threadIdx.x) * 4;
  if (i >= n) return;
  float4 v = *(const float4*)(in + i);
  out[i] = __float2bfloat16(v.x);
  out[i + 1] = __float2bfloat16(v.y);
  out[i + 2] = __float2bfloat16(v.z);
  out[i + 3] = __float2bfloat16(v.w);
}

__global__ void k_badd(const float* __restrict__ a, const float* __restrict__ b,
                       float* __restrict__ o, int n) {
  int i = blockIdx.x * 256 + threadIdx.x;
  if (i < n) o[i] = a[i] + b[i];
}

extern "C" void kernel_launch(void* const* d_in, const int* in_sizes, int n_in,
                              void* d_out, int out_size, void* d_ws, size_t ws_size,
                              hipStream_t stream) {
  const float* obs   = (const float*)d_in[0];
  const float* Wemb  = (const float*)d_in[1];
  const float* bemb  = (const float*)d_in[2];
  const float* Wih0f = (const float*)d_in[3];
  const float* Whh0f = (const float*)d_in[4];
  const float* bih0  = (const float*)d_in[5];
  const float* bhh0  = (const float*)d_in[6];
  const float* Wih1f = (const float*)d_in[7];
  const float* Whh1f = (const float*)d_in[8];
  const float* bih1  = (const float*)d_in[9];
  const float* bhh1  = (const float*)d_in[10];
  const float* W1f   = (const float*)d_in[11];
  const float* b1m   = (const float*)d_in[12];
  const float* W2    = (const float*)d_in[13];
  const float* b2    = (const float*)d_in[14];
  const float* W3    = (const float*)d_in[15];
  const float* b3    = (const float*)d_in[16];

  char* ws = (char*)d_ws;
  size_t off = 0;
  auto alloc = [&](size_t bytes) -> void* {
    void* p = ws + off;
    off += (bytes + 255) & ~(size_t)255;
    return p;
  };
  bf16* wih0 = (bf16*)alloc((size_t)4096 * 256 * 2);
  bf16* whh0 = (bf16*)alloc((size_t)4096 * 1024 * 2);
  bf16* wih1 = (bf16*)alloc((size_t)4096 * 1024 * 2);
  bf16* whh1 = (bf16*)alloc((size_t)4096 * 1024 * 2);
  bf16* w1b  = (bf16*)alloc((size_t)32 * 1024 * 2);
  float* b0c = (float*)alloc((size_t)4096 * 4);
  float* b1c = (float*)alloc((size_t)4096 * 4);
  bf16* emb  = (bf16*)alloc((size_t)8 * NB * NE * 2);
  bf16* h0a  = (bf16*)alloc((size_t)NB * NH * 2);
  bf16* h0b  = (bf16*)alloc((size_t)NB * NH * 2);
  bf16* h1a  = (bf16*)alloc((size_t)NB * NH * 2);
  bf16* h1b  = (bf16*)alloc((size_t)NB * NH * 2);
  float* c0  = (float*)alloc((size_t)NB * NH * 4);
  float* c1  = (float*)alloc((size_t)NB * NH * 4);
  float* curr = (float*)alloc((size_t)NB * 2 * 4);
  bf16* cemb = (bf16*)alloc((size_t)NB * NE * 2);

  k_f2b<<<1024, 256, 0, stream>>>(Wih0f, wih0, 4096 * 256);
  k_f2b<<<4096, 256, 0, stream>>>(Whh0f, whh0, 4096 * 1024);
  k_f2b<<<4096, 256, 0, stream>>>(Wih1f, wih1, 4096 * 1024);
  k_f2b<<<4096, 256, 0, stream>>>(Whh1f, whh1, 4096 * 1024);
  k_f2b<<<32, 256, 0, stream>>>(W1f, w1b, 32 * 1024);
  k_badd<<<16, 256, 0, stream>>>(bih0, bhh0, b0c, 4096);
  k_badd<<<16, 256, 0, stream>>>(bih1, bhh1, b1c, 4096);
  k_embed<<<(8 * NB) / 4, 256, 0, stream>>>(obs, Wemb, bemb, emb);

  bf16* h0buf[2] = {h0a, h0b};
  bf16* h1buf[2] = {h1a, h1b};
  float* preds = (float*)d_out;

  auto mk = [&](const bf16* X, int ldx, int Kx, const bf16* Hin, int Kh,
                const bf16* Wih, const bf16* Whh, const float* bb, float* C,
                bf16* Ho, int cz) {
    CellP q;
    q.X = X; q.Hin = Hin; q.Wih = Wih; q.Whh = Whh;
    q.bias = bb; q.Cst = C; q.Hout = Ho;
    q.ldx = ldx; q.Kx = Kx; q.Kh = Kh; q.czero = cz;
    return q;
  };

  // L0(0): encode step 0, h/c start at zero (Kh=0 -> Hin never read)
  {
    CellP p0 = mk(emb, NE, NE, h0buf[1], 0, wih0, whh0, b0c, c0, h0buf[0], 1);
    k_cell<<<512, 512, 0, stream>>>(p0, p0, 512);
  }
  // encode: fused L1(t) || L0(t+1), t = 0..7 (both depend only on h0(t))
  for (int t = 0; t < 8; ++t) {
    int cu = t & 1, pv = cu ^ 1;
    int kh1 = (t == 0) ? 0 : NH;
    CellP pl1 = mk(h0buf[cu], NH, NH, h1buf[pv], kh1,
                   wih1, whh1, b1c, c1, h1buf[cu], t == 0);
    const bf16* xnext = (t + 1 < 8) ? emb + (size_t)(t + 1) * NB * NE
                                    : emb + (size_t)7 * NB * NE;  // t+1==8: embed(obs[-1])
    CellP pl0 = mk(xnext, NE, NE, h0buf[cu], NH,
                   wih0, whh0, b0c, c0, h0buf[pv], 0);
    k_cell<<<1024, 512, 0, stream>>>(pl1, pl0, 512);
  }
  // decode: serial (L0 input comes from k_mlp of previous step)
  for (int t = 8; t < 20; ++t) {
    int cu = t & 1, pv = cu ^ 1;
    if (t > 8) {
      CellP pl0 = mk(cemb, NE, NE, h0buf[pv], NH,
                     wih0, whh0, b0c, c0, h0buf[cu], 0);
      k_cell<<<512, 512, 0, stream>>>(pl0, pl0, 512);
    }
    CellP pl1 = mk(h0buf[cu], NH, NH, h1buf[pv], NH,
                   wih1, whh1, b1c, c1, h1buf[cu], 0);
    k_cell<<<512, 512, 0, stream>>>(pl1, pl1, 512);
    int pI = t - 8;
    const float* cin = (pI == 0) ? (obs + (size_t)7 * NB * 2) : curr;
    k_mlp<<<NB / 4, 256, 0, stream>>>(h1buf[cu], w1b, b1m, W2, b2, W3, b3,
                                      cin, curr, preds + (size_t)pI * NB * 2,
                                      Wemb, bemb, cemb);
  }
}